// Round 8
// baseline (345.479 us; speedup 1.0000x reference)
//
#include <hip/hip_runtime.h>
#include <cstdint>

#define N_PTS 2097152          // 2^21
#define MASK  (N_PTS - 1)

constexpr int NPOS = 128;      // grid positions per block (pos q in [0,128))
constexpr int POUT = 116;      // outputs per block: g = i0 + tid, tid < 116
constexpr int GOFF = 6;        // g = i0 - GOFF + q
constexpr int BLK  = 256;      // 4 waves; each wave owns TWO 16-pos n-tiles
constexpr int NBLK = (N_PTS + POUT - 1) / POUT;   // 18079 real blocks (+1 tail)

// LDS activation strides (u16 units), all 40 = 80 B (odd multiple of 16 B,
// 2-way-free). L3/L5 biases moved to the MFMA C-operand (from an LDS table),
// which frees the act2/act4 bias columns: ks=1 B-reads now SPILL into the
// next row's channels (finite; A-weights zero there). act3 does not exist
// (L3+L4 fused in registers, R6). LDS = 22,848 B -> 7 blocks/CU.
constexpr int ST1 = 40;    // act1: 20 ch + bias col 20 (L2 bias in-B), rows 0..131
constexpr int ST2 = 40;    // act2: 40 ch, rows 0..127 (+r128 guard c0..23)
constexpr int ST4 = 40;    // act4: 40 ch, rows 1..128 (r0 finite-guard; r129..131 = act1 guard)

constexpr int SLOTA_OFF = 0;
constexpr int SLOTA_SZ  = 10560;   // act1 [132][40]; act4 [<=131][40] (10480 B) aliases
constexpr int SLOTB_OFF = SLOTA_SZ;
constexpr int SLOTB_SZ  = 10320;   // act2 [129][40] (row 128 = guard)
constexpr int SBIAS_OFF = SLOTA_SZ + SLOTB_SZ;      // 20880: 100 f32 (b3|b5, x L2E)
constexpr int TAIL_OFF  = SBIAS_OFF + 100 * 4;      // 21280
// tail f32: sdif 132 | sw6 20 | sb6 1 | sbm 118 | su 121 = 392
constexpr int SMEM_BYTES = TAIL_OFF + 392 * 4;      // 22848 -> 7 blocks/CU

// precomputed f16 A-fragments in d_ws (u16 units); frag idx = (t*MT+mt)*KS+ks
constexpr int F2 = 0;          // L2: 5 taps x MT3 x KS1 = 15 frags x 512 u16
constexpr int F3 = 7680;       // L3: 1 x 5 x 2 = 10 (no bias; bias via C)
constexpr int F4 = 12800;      // L4: 1 x 3 x 3 = 9 (k-PERMUTED, bias in-B)
constexpr int F5 = 17408;      // L5: 3 x 2 x 2 = 12 (no bias; bias via C)
constexpr int F1 = 23552;      // L1: 2 frags (MT=2, taps+bias in k)  -> ends 24576
constexpr int NFRAG2 = 15, NFRAG3 = 10, NFRAG4 = 9, NFRAG5 = 12;
constexpr int NPREP = NFRAG2 + NFRAG3 + NFRAG4 + NFRAG5 + 2;   // 48
constexpr int BIAS_OFF = 49152;   // d_ws f32 bias table (x L2E): b3[80] | b5[20]
constexpr int BME_OFF = 65536; // 4 edge bm values (f32): bm[0], bm[1], bm[N-2], bm[N-1]

// log2e folding: every stored activation is act' = L2E*elu(x); pre-activations
// t = L2E*x come straight out of the MFMA (weights unchanged, biases *L2E,
// layer-1 W&b *L2E, w6 *LN2 at stage). ELU becomes exp2-native.
constexpr float L2E = 1.4426950408889634f;
constexpr float LN2 = 0.6931471805599453f;

typedef _Float16 f16x8 __attribute__((ext_vector_type(8)));
typedef _Float16 f16x2 __attribute__((ext_vector_type(2)));
typedef unsigned short u16x8 __attribute__((ext_vector_type(8)));
typedef float f32x4 __attribute__((ext_vector_type(4)));

constexpr unsigned short F16_ONE = 0x3C00;

extern "C" __device__ _Float16 __ocml_exp2_f16(_Float16);

__device__ __forceinline__ float fastrcp(float x) {
#if __has_builtin(__builtin_amdgcn_rcpf)
    return __builtin_amdgcn_rcpf(x);
#else
    return 1.f / x;
#endif
}

__device__ __forceinline__ float fastexp2(float x) {
#if __has_builtin(__builtin_amdgcn_exp2f)
    return __builtin_amdgcn_exp2f(x);
#else
    return __expf(x * LN2);
#endif
}

// scalar ELU' on t=L2E*x: returns L2E*elu(x) = max(t, L2E*(2^min(t,0)-1))
__device__ __forceinline__ float elu_t(float t) {
    const float e = fastexp2(fminf(t, 0.f));
    return fmaxf(t, fmaf(e, L2E, -L2E));
}

// f32 -> f16 RTNE (weights, once in prep)
__device__ __forceinline__ unsigned short f2h_rtne(float f) {
    return __builtin_bit_cast(unsigned short, (_Float16)f);
}

// packed-f16 ELU' on pre-scaled t: act' = max(t, fma(2^min(t,0), L2E, -L2E)).
// Positive branch exact (2^0*L2E-L2E = 0). 6 insts / 2 elements.
__device__ __forceinline__ unsigned int elu2_pk(float t0, float t1) {
    f16x2 h = __builtin_bit_cast(f16x2, __builtin_amdgcn_cvt_pkrtz(t0, t1));
    const f16x2 z = {(_Float16)0.f, (_Float16)0.f};
    f16x2 m = __builtin_elementwise_min(h, z);
    f16x2 e;
    e[0] = __ocml_exp2_f16(m[0]);
    e[1] = __ocml_exp2_f16(m[1]);
    const f16x2 l2e2  = {(_Float16)L2E, (_Float16)L2E};
    const f16x2 nl2e2 = {(_Float16)(-L2E), (_Float16)(-L2E)};
    f16x2 el = __builtin_elementwise_fma(e, l2e2, nl2e2);
    f16x2 r = __builtin_elementwise_max(h, el);
    return __builtin_bit_cast(unsigned int, r);
}

// f32 pair -> packed f16 (RTZ), for the L1 im2col B build
__device__ __forceinline__ unsigned int cvt_pkrtz_u(float lo, float hi) {
    return __builtin_bit_cast(unsigned int, __builtin_amdgcn_cvt_pkrtz(lo, hi));
}

// ---------------------------------------------------------------------------
// Prep: one fragment per block. RTNE, zero-padded m/k.
// biasTap >= 0: bias folded at k == CI on that tap (x L2E), bias col holds 1.0.
// biasTap <  0: no in-matrix bias (bias via C-operand from the LDS table).
// Block 0 also writes the L2E-scaled f32 bias table (b3|b5) and re-arms bmE.
// ---------------------------------------------------------------------------
template<int M, int MT, int CI, int KS, int KT>
__device__ __forceinline__ void pack_one(const float* __restrict__ W,
                                         const float* __restrict__ Bias, int biasTap,
                                         unsigned short* __restrict__ dst,
                                         int f, int lane)
{
    const int ks = f % KS;
    const int fi = f / KS;
    const int mt = fi % MT;
    const int t  = fi / MT;
    const int m  = mt * 16 + (lane & 15);
    const int kb = ks * 32 + (lane >> 4) * 8;
    u16x8 v;
    #pragma unroll
    for (int j = 0; j < 8; ++j) {
        const int k = kb + j;
        float val = 0.f;
        if (m < M) {
            if (k < CI)                          val = W[(m * CI + k) * KT + t];
            else if (k == CI && t == biasTap)    val = Bias[m] * L2E;
        }
        v[j] = f2h_rtne(val);
    }
    *(u16x8*)(dst + (f * 64 + lane) * 8) = v;
}

__global__ __launch_bounds__(64) void prep_kernel(
    const float* __restrict__ w1, const float* __restrict__ b1,
    const float* __restrict__ w2, const float* __restrict__ b2,
    const float* __restrict__ w3, const float* __restrict__ b3,
    const float* __restrict__ w4, const float* __restrict__ b4,
    const float* __restrict__ w5, const float* __restrict__ b5,
    unsigned short* __restrict__ frags,
    float* __restrict__ biasT,
    float* __restrict__ bmE)
{
    const int lane = threadIdx.x;
    const int b = blockIdx.x;
    if (b == 0) {
        if (lane < 4) bmE[lane] = 0.f;   // "not ready" sentinel
        for (int i = lane; i < 100; i += 64) {
            const float v = (i < 80) ? b3[i] : b5[i - 80];
            biasT[i] = v * L2E;
        }
    }
    if (b < NFRAG2)
        pack_one<40, 3, 20, 1, 5>(w2, b2, 2, frags + F2, b, lane);
    else if (b < NFRAG2 + NFRAG3)
        pack_one<80, 5, 40, 2, 1>(w3, b3, -1, frags + F3, b - NFRAG2, lane);
    else if (b < NFRAG2 + NFRAG3 + NFRAG4) {
        // F4: k-PERMUTED so L3's D-layout feeds directly as B.
        // k' = ks*32 + q*8 + j  maps to logical channel:
        //   ks<2        : ch = ks*32 + (j>>2)*16 + q*4 + (j&3)
        //   ks==2, j<4  : ch = 64 + q*4 + j
        //   ks==2, j==4, q==0 : bias slot (B side provides 1.0)
        //   else        : zero
        const int f  = b - NFRAG2 - NFRAG3;   // f = mt*3 + ks
        const int ks = f % 3;
        const int mt = f / 3;
        const int m  = mt * 16 + (lane & 15);
        const int q  = lane >> 4;
        u16x8 v;
        #pragma unroll
        for (int j = 0; j < 8; ++j) {
            float val = 0.f;
            if (m < 40) {
                if (ks < 2) {
                    const int ch = ks * 32 + ((j >> 2) << 4) + q * 4 + (j & 3);
                    val = w4[m * 80 + ch];
                } else if (j < 4) {
                    const int ch = 64 + q * 4 + j;
                    val = w4[m * 80 + ch];
                } else if (j == 4 && q == 0) {
                    val = b4[m] * L2E;
                }
            }
            v[j] = f2h_rtne(val);
        }
        *(u16x8*)(frags + F4 + (f * 64 + lane) * 8) = v;
    }
    else if (b < NFRAG2 + NFRAG3 + NFRAG4 + NFRAG5)
        pack_one<20, 2, 40, 2, 3>(w5, b5, -1, frags + F5, b - NFRAG2 - NFRAG3 - NFRAG4, lane);
    else {
        // L1 fragments: A[m][k], k=0..4 -> w1 taps * L2E, k=5 -> bias * L2E.
        const int mt = b - (NPREP - 2);
        const int m  = mt * 16 + (lane & 15);
        const int kb = (lane >> 4) * 8;
        u16x8 v;
        #pragma unroll
        for (int j = 0; j < 8; ++j) {
            const int k = kb + j;
            float val = 0.f;
            if (m < 20) {
                if (k < 5)      val = w1[m * 5 + k] * L2E;
                else if (k == 5) val = b1[m] * L2E;
            }
            v[j] = f2h_rtne(val);
        }
        *(u16x8*)(frags + F1 + (mt * 64 + lane) * 8) = v;
    }
}

template<int NF>
__device__ __forceinline__ void load_A(const unsigned short* __restrict__ Af,
                                       int lane, f16x8* A) {
    #pragma unroll
    for (int f = 0; f < NF; ++f)
        A[f] = __builtin_bit_cast(f16x8, *(const u16x8*)(Af + (f * 64 + lane) * 8));
}

// ---------------------------------------------------------------------------
// Tap-decomposed MFMA layer; wave wv owns n-tiles 2wv, 2wv+1.
// ALL B-loads (both n-tiles) are hoisted above the MFMA+epilogue work so the
// epilogue LDS stores of tile 0 cannot block tile 1's loads.
// ---------------------------------------------------------------------------
template<int TAPS, int MT, int KS, typename Epi>
__device__ __forceinline__ void gemm_tap(const unsigned short* __restrict__ Af,
                                         const unsigned short* __restrict__ Bbuf,
                                         int SB, f32x4 Z4, Epi epi)
{
    const int lane = threadIdx.x & 63;
    const int wv   = threadIdx.x >> 6;
    const int n15  = lane & 15;
    const int quad = lane >> 4;

    f16x8 A[TAPS * MT * KS];
    load_A<TAPS * MT * KS>(Af, lane, A);

    f16x8 B[2][TAPS][KS];
    #pragma unroll
    for (int nt = 0; nt < 2; ++nt) {
        const int pos = (wv * 2 + nt) * 16 + n15;
        #pragma unroll
        for (int t = 0; t < TAPS; ++t)
            #pragma unroll
            for (int ks = 0; ks < KS; ++ks)
                B[nt][t][ks] = __builtin_bit_cast(f16x8,
                    *(const u16x8*)(Bbuf + (pos + t) * SB + ks * 32 + quad * 8));
    }

    #pragma unroll
    for (int nt = 0; nt < 2; ++nt) {
        const int pos = (wv * 2 + nt) * 16 + n15;
        #pragma unroll
        for (int mt = 0; mt < MT; ++mt) {
            f32x4 acc = __builtin_amdgcn_mfma_f32_16x16x32_f16(
                A[mt * KS], B[nt][0][0], Z4, 0, 0, 0);
            #pragma unroll
            for (int i = 1; i < TAPS * KS; ++i) {
                const int t = i / KS, ks = i - t * KS;
                acc = __builtin_amdgcn_mfma_f32_16x16x32_f16(
                    A[(t * MT + mt) * KS + ks], B[nt][t][ks], acc, 0, 0, 0);
            }
            epi(mt, pos, acc);
        }
    }
}

// ---------------------------------------------------------------------------
// WENO5 math given the 6-point u stencil and 3 bm values (rcp-based)
// ---------------------------------------------------------------------------
__device__ __forceinline__ float weno_math(float um2, float um1, float u0,
                                           float up1, float up2, float up3,
                                           float bmm, float bm0, float bmp)
{
    const float c1312 = 13.f / 12.f;
    const float s6 = 1.f / 6.f;

    const float f0p = (11.f * up1 - 7.f * up2 + 2.f * up3) * s6;
    const float f1p = (2.f * u0 + 5.f * up1 - up2) * s6;
    const float f2p = (-um1 + 5.f * u0 + 2.f * up1) * s6;
    const float f0n = (11.f * u0 - 7.f * up1 + 2.f * up2) * s6;
    const float f1n = (2.f * um1 + 5.f * u0 - up1) * s6;
    const float f2n = (-um2 + 5.f * um1 + 2.f * u0) * s6;

    float t0, t1;
    t0 = up1 - 2.f * up2 + up3;  t1 = 3.f * up1 - 4.f * up2 + up3;
    float bp0 = c1312 * t0 * t0 + 0.25f * t1 * t1;
    t0 = u0 - 2.f * up1 + up2;   t1 = u0 - up2;
    float bp1 = c1312 * t0 * t0 + 0.25f * t1 * t1;
    t0 = um1 - 2.f * u0 + up1;   t1 = um1 - 4.f * u0 + 3.f * up1;
    float bp2 = c1312 * t0 * t0 + 0.25f * t1 * t1;
    t0 = u0 - 2.f * up1 + up2;   t1 = 3.f * u0 - 4.f * up1 + up2;
    float bn0 = c1312 * t0 * t0 + 0.25f * t1 * t1;
    t0 = um1 - 2.f * u0 + up1;   t1 = um1 - up1;
    float bn1 = c1312 * t0 * t0 + 0.25f * t1 * t1;
    t0 = um2 - 2.f * um1 + u0;   t1 = um2 - 4.f * um1 + 3.f * u0;
    float bn2 = c1312 * t0 * t0 + 0.25f * t1 * t1;

    bp0 *= bmp; bp1 *= bm0; bp2 *= bmm;
    bn0 *= bmp; bn1 *= bm0; bn2 *= bmm;

    const float E = 1e-13f;
    float brs, e, r0, r1, r2, o0, o1, o2;

    brs = bp2 - bp0; brs *= brs;
    e = E + bp0; e *= e; r0 = fastrcp(e);
    e = E + bp1; e *= e; r1 = fastrcp(e);
    e = E + bp2; e *= e; r2 = fastrcp(e);
    o0 = 0.1f * fmaf(brs, r0, 1.f);
    o1 = 0.6f * fmaf(brs, r1, 1.f);
    o2 = 0.3f * fmaf(brs, r2, 1.f);
    const float fluxp = (o0 * f0p + o1 * f1p + o2 * f2p) * fastrcp(o0 + o1 + o2);

    brs = bn2 - bn0; brs *= brs;
    e = E + bn0; e *= e; r0 = fastrcp(e);
    e = E + bn1; e *= e; r1 = fastrcp(e);
    e = E + bn2; e *= e; r2 = fastrcp(e);
    o0 = 0.1f * fmaf(brs, r0, 1.f);
    o1 = 0.6f * fmaf(brs, r1, 1.f);
    o2 = 0.3f * fmaf(brs, r2, 1.f);
    const float fluxn = (o0 * f0n + o1 * f1n + o2 * f2n) * fastrcp(o0 + o1 + o2);

    return fluxp - fluxn;
}

// ---------------------------------------------------------------------------
// Fused CNN + WENO (256 threads = 4 waves; two n-tiles per wave).
// ---------------------------------------------------------------------------
__global__ __launch_bounds__(BLK, 7) void cnn_weno_kernel(
    const float* __restrict__ u,
    const float* __restrict__ w6, const float* __restrict__ b6,
    const unsigned short* __restrict__ frags,
    const float* __restrict__ biasTg,
    float* __restrict__ bmE,
    float* __restrict__ out)
{
    // ---- tail block: spin on the 4 ready-slots, then patch wrap points ----
    if (blockIdx.x == NBLK) {
        if (threadIdx.x == 0) {
            float b0, b1, b2, b3;
            for (;;) {
                b0 = __hip_atomic_load(&bmE[0], __ATOMIC_ACQUIRE, __HIP_MEMORY_SCOPE_AGENT);
                b1 = __hip_atomic_load(&bmE[1], __ATOMIC_ACQUIRE, __HIP_MEMORY_SCOPE_AGENT);
                b2 = __hip_atomic_load(&bmE[2], __ATOMIC_ACQUIRE, __HIP_MEMORY_SCOPE_AGENT);
                b3 = __hip_atomic_load(&bmE[3], __ATOMIC_ACQUIRE, __HIP_MEMORY_SCOPE_AGENT);
                if (b0 != 0.f && b1 != 0.f && b2 != 0.f && b3 != 0.f) break;
                __builtin_amdgcn_s_sleep(2);
            }
            out[0] = weno_math(u[N_PTS - 2], u[N_PTS - 1], u[0],
                               u[1], u[2], u[3], b3, b0, b1);
            out[N_PTS - 1] = weno_math(u[N_PTS - 3], u[N_PTS - 2], u[N_PTS - 1],
                                       u[0], u[1], u[2], b2, b3, b0);
        }
        return;
    }

    extern __shared__ char smem[];
    unsigned short* act1 = (unsigned short*)(smem + SLOTA_OFF);  // [132][40], dead after P3
    unsigned short* act4 = (unsigned short*)(smem + SLOTA_OFF);  // [<=131][40], written P4
    unsigned short* act2 = (unsigned short*)(smem + SLOTB_OFF);  // [129][40]
    float* sbias = (float*)(smem + SBIAS_OFF); // 100: b3[80] | b5[20]  (x L2E)
    float* sdif = (float*)(smem + TAIL_OFF);   // 132
    float* sw6  = sdif + 132;                  // 20
    float* sb6  = sw6 + 20;                    // 1
    float* sbm  = sb6 + 1;                     // 118  (sbm[j] = bm at q = j + 5)
    float* su   = sbm + 118;                   // 121  (su[j] = u[(i0-2+j) & MASK])

    const int tid  = threadIdx.x;
    const int lane = tid & 63;
    const int wv   = tid >> 6;
    const int n15  = lane & 15;
    const int quad = lane >> 4;
    const int i0   = blockIdx.x * POUT;
    const bool edge = (blockIdx.x == 0) || (blockIdx.x >= NBLK - 1);

    const f32x4 Z4 = {0.f, 0.f, 0.f, 0.f};     // hoisted zero C-operand

    // ---- phase 1: stale-read guards + bias table + staging ----
    {
        const u16x8 z8 = {0, 0, 0, 0, 0, 0, 0, 0};
        // act1 rows 128..131 (cols 0..39): L2 tap reads + doubles as act4
        // rows 128..131 guard (alias). act2 r128 c0..23: L3 ks-spill from r127.
        // act4 r0 c0..39: finite-only (L5 pos<5 outputs are discarded); P2
        // overwrites c0..31 with act1 data, c32..39 keep the zero.
        if (tid < 20)       *(u16x8*)(act1 + 128 * ST1 + tid * 8) = z8;
        else if (tid < 23)  *(u16x8*)(act2 + 128 * ST2 + (tid - 20) * 8) = z8;
        else if (tid < 28)  *(u16x8*)(act4 + (tid - 23) * 8) = z8;
        if (tid < 100) sbias[tid] = biasTg[tid];
    }
    if (!edge) {   // fast path: no boundary handling needed (uniform branch)
        for (int d = tid; d < 132; d += BLK) {
            const int g = i0 - 10 + d;
            sdif[d] = 0.5f * (u[g + 1] - u[g - 1]);
        }
        for (int j = tid; j < 121; j += BLK)
            su[j] = u[i0 - 2 + j];
    } else {
        for (int d = tid; d < 132; d += BLK) {
            const int g = i0 - 10 + d;
            float v = 0.f;
            if (g >= 0 && g < N_PTS) {
                if (g == 0)              v = u[1] - u[0];
                else if (g == N_PTS - 1) v = u[N_PTS - 1] - u[N_PTS - 2];
                else                     v = 0.5f * (u[g + 1] - u[g - 1]);
            }
            sdif[d] = v;
        }
        for (int j = tid; j < 121; j += BLK)
            su[j] = u[(i0 - 2 + j) & MASK];
    }
    if (tid < 20)       sw6[tid] = w6[tid] * LN2;   // log2e-folding: w6*ln2
    else if (tid == 20) sb6[0] = b6[0];
    __syncthreads();

    // ---- phase 2: L1 via MFMA (im2col B from sdif; taps+bias in k) ----
    {
        f16x8 A1[2];
        load_A<2>(frags + F1, lane, A1);
        float s[2][5];
        #pragma unroll
        for (int nt = 0; nt < 2; ++nt) {
            const int pos = (wv * 2 + nt) * 16 + n15;
            #pragma unroll
            for (int j = 0; j < 5; ++j)
                s[nt][j] = sdif[pos + j];
        }
        #pragma unroll
        for (int nt = 0; nt < 2; ++nt) {
            const int pos = (wv * 2 + nt) * 16 + n15;
            uint4 bd;
            bd.x = cvt_pkrtz_u(s[nt][0], s[nt][1]);
            bd.y = cvt_pkrtz_u(s[nt][2], s[nt][3]);
            bd.z = cvt_pkrtz_u(s[nt][4], 1.0f);    // k=5 bias slot
            bd.w = 0u;
            const f16x8 B = __builtin_bit_cast(f16x8, bd);
            const f32x4 a0 = __builtin_amdgcn_mfma_f32_16x16x32_f16(A1[0], B, Z4, 0, 0, 0);
            const f32x4 a1 = __builtin_amdgcn_mfma_f32_16x16x32_f16(A1[1], B, Z4, 0, 0, 0);
            bool oor = false;
            if (edge) {
                const int g = i0 + pos - 8;   // act1 row pos <-> g
                oor = ((unsigned)g >= (unsigned)N_PTS);
            }
            {   // ch 0..15
                uint2 w;
                w.x = elu2_pk(a0[0], a0[1]); w.y = elu2_pk(a0[2], a0[3]);
                if (oor) { w.x = 0u; w.y = 0u; }
                *(uint2*)(act1 + pos * ST1 + quad * 4) = w;
            }
            {   // ch 16..19 + bias col 20 (L2 bias in-B) + zero pad 24..31
                uint2 w;
                if (quad == 0) {
                    w.x = elu2_pk(a1[0], a1[1]); w.y = elu2_pk(a1[2], a1[3]);
                    if (oor) { w.x = 0u; w.y = 0u; }
                } else if (quad == 1) {
                    w.x = (unsigned)F16_ONE; w.y = 0u;
                } else {
                    w.x = 0u; w.y = 0u;
                }
                *(uint2*)(act1 + pos * ST1 + 16 + quad * 4) = w;
            }
        }
    }
    __syncthreads();

    // ---- phase 3: L2 (40ch, 5 taps, bias folded in-B) act1 -> act2 ----
    gemm_tap<5, 3, 1>(frags + F2, act1, ST1, Z4,
        [&](int mt, int pos, f32x4 acc) {
            if (mt < 2 || quad < 2) {        // ch0 < 40
                uint2 w;
                w.x = elu2_pk(acc[0], acc[1]); w.y = elu2_pk(acc[2], acc[3]);
                if (edge) {
                    const int g = i0 - GOFF + pos;
                    if ((unsigned)g >= (unsigned)N_PTS) { w.x = 0u; w.y = 0u; }
                }
                *(uint2*)(act2 + pos * ST2 + mt * 16 + quad * 4) = w;
            }
        });
    __syncthreads();

    // ---- phase 4: L3+L4 FUSED in registers (both k=1) act2 -> act4.
    //      L3 bias via C-operand (LDS sbias); L3's D-layout feeds L4's B
    //      directly via the k-permuted F4 frags (L4 bias in-B).
    {
        unsigned int p[2][5][2];   // packed elu'(L3) f16 pairs (static-indexed)
        {
            f16x8 A3[10];
            load_A<10>(frags + F3, lane, A3);
            f16x8 B3[2][2];
            #pragma unroll
            for (int nt = 0; nt < 2; ++nt) {
                const int pos = (wv * 2 + nt) * 16 + n15;
                #pragma unroll
                for (int ks = 0; ks < 2; ++ks)
                    B3[nt][ks] = __builtin_bit_cast(f16x8,
                        *(const u16x8*)(act2 + pos * ST2 + ks * 32 + quad * 8));
            }
            #pragma unroll
            for (int mt = 0; mt < 5; ++mt) {
                const f32x4 c3 = *(const f32x4*)(sbias + mt * 16 + quad * 4);
                #pragma unroll
                for (int nt = 0; nt < 2; ++nt) {
                    f32x4 acc = __builtin_amdgcn_mfma_f32_16x16x32_f16(
                        A3[mt * 2 + 0], B3[nt][0], c3, 0, 0, 0);
                    acc = __builtin_amdgcn_mfma_f32_16x16x32_f16(
                        A3[mt * 2 + 1], B3[nt][1], acc, 0, 0, 0);
                    p[nt][mt][0] = elu2_pk(acc[0], acc[1]);
                    p[nt][mt][1] = elu2_pk(acc[2], acc[3]);
                }
            }
        }
        {
            f16x8 A4[9];
            load_A<9>(frags + F4, lane, A4);
            const unsigned int biasw = (quad == 0) ? (unsigned)F16_ONE : 0u;
            #pragma unroll
            for (int nt = 0; nt < 2; ++nt) {
                const int pos = (wv * 2 + nt) * 16 + n15;
                uint4 w0, w1, w2;
                w0.x = p[nt][0][0]; w0.y = p[nt][0][1]; w0.z = p[nt][1][0]; w0.w = p[nt][1][1];
                w1.x = p[nt][2][0]; w1.y = p[nt][2][1]; w1.z = p[nt][3][0]; w1.w = p[nt][3][1];
                w2.x = p[nt][4][0]; w2.y = p[nt][4][1]; w2.z = biasw;       w2.w = 0u;
                f16x8 B4[3];
                B4[0] = __builtin_bit_cast(f16x8, w0);
                B4[1] = __builtin_bit_cast(f16x8, w1);
                B4[2] = __builtin_bit_cast(f16x8, w2);
                #pragma unroll
                for (int mt = 0; mt < 3; ++mt) {
                    f32x4 acc = __builtin_amdgcn_mfma_f32_16x16x32_f16(
                        A4[mt * 3 + 0], B4[0], Z4, 0, 0, 0);
                    acc = __builtin_amdgcn_mfma_f32_16x16x32_f16(
                        A4[mt * 3 + 1], B4[1], acc, 0, 0, 0);
                    acc = __builtin_amdgcn_mfma_f32_16x16x32_f16(
                        A4[mt * 3 + 2], B4[2], acc, 0, 0, 0);
                    if (mt < 2 || quad < 2) {    // ch0 < 40
                        uint2 w;
                        w.x = elu2_pk(acc[0], acc[1]); w.y = elu2_pk(acc[2], acc[3]);
                        if (edge) {
                            const int g = i0 - GOFF + pos;
                            if ((unsigned)g >= (unsigned)N_PTS) { w.x = 0u; w.y = 0u; }
                        }
                        *(uint2*)(act4 + (pos + 1) * ST4 + mt * 16 + quad * 4) = w;
                    }
                }
            }
        }
    }
    __syncthreads();

    // ---- phase 6: L5 (20ch, 3 taps, bias via C) + L6 + sigmoid -> sbm ----
    {
        f16x8 A5[12];
        load_A<12>(frags + F5, lane, A5);
        const f32x4 c0 = *(const f32x4*)(sbias + 80 + quad * 4);
        const f32x4 c1 = *(const f32x4*)(sbias + 80 + 16);
        #pragma unroll
        for (int nt = 0; nt < 2; ++nt) {
            const int pos = (wv * 2 + nt) * 16 + n15;
            f16x8 B[3][2];
            #pragma unroll
            for (int t = 0; t < 3; ++t)
                #pragma unroll
                for (int ks = 0; ks < 2; ++ks)
                    B[t][ks] = __builtin_bit_cast(f16x8,
                        *(const u16x8*)(act4 + (pos + t) * ST4 + ks * 32 + quad * 8));
            f32x4 a0 = __builtin_amdgcn_mfma_f32_16x16x32_f16(A5[0], B[0][0], c0, 0, 0, 0);
            f32x4 a1 = __builtin_amdgcn_mfma_f32_16x16x32_f16(A5[2], B[0][0], c1, 0, 0, 0);
            #pragma unroll
            for (int i = 1; i < 6; ++i) {
                const int t = i >> 1, ks = i & 1;
                a0 = __builtin_amdgcn_mfma_f32_16x16x32_f16(
                    A5[(t * 2 + 0) * 2 + ks], B[t][ks], a0, 0, 0, 0);
                a1 = __builtin_amdgcn_mfma_f32_16x16x32_f16(
                    A5[(t * 2 + 1) * 2 + ks], B[t][ks], a1, 0, 0, 0);
            }
            float partial = 0.f;
            const int c0i = quad * 4;
            #pragma unroll
            for (int r = 0; r < 4; ++r)
                partial += sw6[c0i + r] * elu_t(a0[r]);
            if (quad == 0) {
                #pragma unroll
                for (int r = 0; r < 4; ++r)
                    partial += sw6[16 + r] * elu_t(a1[r]);
            }
            partial += __shfl_xor(partial, 16, 64);
            partial += __shfl_xor(partial, 32, 64);
            if (quad == 0) {
                const float bmv = fastrcp(1.f + __expf(-(partial + sb6[0]))) + 0.1f;
                if (pos >= 5 && pos < 123) sbm[pos - 5] = bmv;
                if (edge) {
                    const int g = i0 - GOFF + pos;
                    if (blockIdx.x == 0) {
                        if (g == 0)
                            __hip_atomic_store(&bmE[0], bmv, __ATOMIC_RELEASE, __HIP_MEMORY_SCOPE_AGENT);
                        else if (g == 1)
                            __hip_atomic_store(&bmE[1], bmv, __ATOMIC_RELEASE, __HIP_MEMORY_SCOPE_AGENT);
                    }
                    if (blockIdx.x == NBLK - 1) {
                        if (g == N_PTS - 2)
                            __hip_atomic_store(&bmE[2], bmv, __ATOMIC_RELEASE, __HIP_MEMORY_SCOPE_AGENT);
                        else if (g == N_PTS - 1)
                            __hip_atomic_store(&bmE[3], bmv, __ATOMIC_RELEASE, __HIP_MEMORY_SCOPE_AGENT);
                    }
                }
            }
        }
    }
    __syncthreads();

    // ---- phase 7: WENO from the staged u tile (wrap handled at staging) ----
    if (tid < POUT) {
        const int g = i0 + tid;
        if (g < N_PTS && g != 0 && g != N_PTS - 1) {
            out[g] = weno_math(su[tid], su[tid + 1], su[tid + 2],
                               su[tid + 3], su[tid + 4], su[tid + 5],
                               sbm[tid], sbm[tid + 1], sbm[tid + 2]);
        }
    }
}

extern "C" void kernel_launch(void* const* d_in, const int* in_sizes, int n_in,
                              void* d_out, int out_size, void* d_ws, size_t ws_size,
                              hipStream_t stream) {
    const float* u  = (const float*)d_in[0];
    const float* w1 = (const float*)d_in[1];
    const float* b1 = (const float*)d_in[2];
    const float* w2 = (const float*)d_in[3];
    const float* b2 = (const float*)d_in[4];
    const float* w3 = (const float*)d_in[5];
    const float* b3 = (const float*)d_in[6];
    const float* w4 = (const float*)d_in[7];
    const float* b4 = (const float*)d_in[8];
    const float* w5 = (const float*)d_in[9];
    const float* b5 = (const float*)d_in[10];
    const float* w6 = (const float*)d_in[11];
    const float* b6 = (const float*)d_in[12];

    unsigned short* frags = (unsigned short*)d_ws;            // 49152 B
    float* biasT = (float*)((char*)d_ws + BIAS_OFF);          // 100 f32 (x L2E)
    float* bmE = (float*)((char*)d_ws + BME_OFF);             // 4 f32 ready-slots

    (void)hipFuncSetAttribute((const void*)cnn_weno_kernel,
                              hipFuncAttributeMaxDynamicSharedMemorySize,
                              SMEM_BYTES);

    prep_kernel<<<NPREP, 64, 0, stream>>>(w1, b1, w2, b2, w3, b3, w4, b4, w5, b5,
                                          frags, biasT, bmE);
    cnn_weno_kernel<<<NBLK + 1, BLK, SMEM_BYTES, stream>>>(u, w6, b6, frags, biasT,
                                                           bmE, (float*)d_out);
}

// Round 9
// 237.542 us; speedup vs baseline: 1.4544x; 1.4544x over previous
//
#include <hip/hip_runtime.h>
#include <cstdint>

#define N_PTS 2097152          // 2^21
#define MASK  (N_PTS - 1)

constexpr int NPOS = 128;      // grid positions per block (pos q in [0,128))
constexpr int POUT = 116;      // outputs per block: g = i0 + tid, tid < 116
constexpr int GOFF = 6;        // g = i0 - GOFF + q
constexpr int BLK  = 256;      // 4 waves; each wave owns TWO 16-pos n-tiles
constexpr int NBLK = (N_PTS + POUT - 1) / POUT;   // 18079 real blocks (+1 tail)

// LDS activation strides (u16 units), all 40 = 80 B (odd multiple of 16 B,
// 2-way-free). L3/L5 biases via MFMA C-operand (LDS table) -> no bias columns;
// ks=1 B-reads SPILL into the next row's channels (finite; A-weights zero).
// act3 does not exist (L3+L4 fused in registers). LDS = 22,848 B.
// NOTE: __launch_bounds__ min-waves stays at 5 (VGPR cap 102) — R8 showed
// that a bound of 7 (cap 73) makes the allocator spill to scratch (VGPR=36,
// WRITE_SIZE 620 MB). Actual usage ~48-64 VGPR -> HW still fits 7 blocks/CU
// since occupancy is computed from ACTUAL usage, not the bound.
constexpr int ST1 = 40;    // act1: 20 ch + bias col 20 (L2 bias in-B), rows 0..131
constexpr int ST2 = 40;    // act2: 40 ch, rows 0..127 (+r128 guard c0..23)
constexpr int ST4 = 40;    // act4: 40 ch, rows 1..128 (r0 finite-guard; r129..131 = act1 guard)

constexpr int SLOTA_OFF = 0;
constexpr int SLOTA_SZ  = 10560;   // act1 [132][40]; act4 [<=131][40] (10480 B) aliases
constexpr int SLOTB_OFF = SLOTA_SZ;
constexpr int SLOTB_SZ  = 10320;   // act2 [129][40] (row 128 = guard)
constexpr int SBIAS_OFF = SLOTA_SZ + SLOTB_SZ;      // 20880: 100 f32 (b3|b5, x L2E)
constexpr int TAIL_OFF  = SBIAS_OFF + 100 * 4;      // 21280
// tail f32: sdif 132 | sw6 20 | sb6 1 | sbm 118 | su 121 = 392
constexpr int SMEM_BYTES = TAIL_OFF + 392 * 4;      // 22848 -> 7 blocks/CU by LDS

// precomputed f16 A-fragments in d_ws (u16 units); frag idx = (t*MT+mt)*KS+ks
constexpr int F2 = 0;          // L2: 5 taps x MT3 x KS1 = 15 frags x 512 u16
constexpr int F3 = 7680;       // L3: 1 x 5 x 2 = 10 (no bias; bias via C)
constexpr int F4 = 12800;      // L4: 1 x 3 x 3 = 9 (k-PERMUTED, bias in-B)
constexpr int F5 = 17408;      // L5: 3 x 2 x 2 = 12 (no bias; bias via C)
constexpr int F1 = 23552;      // L1: 2 frags (MT=2, taps+bias in k)  -> ends 24576
constexpr int NFRAG2 = 15, NFRAG3 = 10, NFRAG4 = 9, NFRAG5 = 12;
constexpr int NPREP = NFRAG2 + NFRAG3 + NFRAG4 + NFRAG5 + 2;   // 48
constexpr int BIAS_OFF = 49152;   // d_ws f32 bias table (x L2E): b3[80] | b5[20]
constexpr int BME_OFF = 65536; // 4 edge bm values (f32): bm[0], bm[1], bm[N-2], bm[N-1]

// log2e folding: every stored activation is act' = L2E*elu(x); pre-activations
// t = L2E*x come straight out of the MFMA (weights unchanged, biases *L2E,
// layer-1 W&b *L2E, w6 *LN2 at stage). ELU becomes exp2-native.
constexpr float L2E = 1.4426950408889634f;
constexpr float LN2 = 0.6931471805599453f;

typedef _Float16 f16x8 __attribute__((ext_vector_type(8)));
typedef _Float16 f16x2 __attribute__((ext_vector_type(2)));
typedef unsigned short u16x8 __attribute__((ext_vector_type(8)));
typedef float f32x4 __attribute__((ext_vector_type(4)));

constexpr unsigned short F16_ONE = 0x3C00;

extern "C" __device__ _Float16 __ocml_exp2_f16(_Float16);

__device__ __forceinline__ float fastrcp(float x) {
#if __has_builtin(__builtin_amdgcn_rcpf)
    return __builtin_amdgcn_rcpf(x);
#else
    return 1.f / x;
#endif
}

__device__ __forceinline__ float fastexp2(float x) {
#if __has_builtin(__builtin_amdgcn_exp2f)
    return __builtin_amdgcn_exp2f(x);
#else
    return __expf(x * LN2);
#endif
}

// scalar ELU' on t=L2E*x: returns L2E*elu(x) = max(t, L2E*(2^min(t,0)-1))
__device__ __forceinline__ float elu_t(float t) {
    const float e = fastexp2(fminf(t, 0.f));
    return fmaxf(t, fmaf(e, L2E, -L2E));
}

// f32 -> f16 RTNE (weights, once in prep)
__device__ __forceinline__ unsigned short f2h_rtne(float f) {
    return __builtin_bit_cast(unsigned short, (_Float16)f);
}

// packed-f16 ELU' on pre-scaled t: act' = max(t, fma(2^min(t,0), L2E, -L2E)).
// Positive branch exact (2^0*L2E-L2E = 0). 6 insts / 2 elements.
__device__ __forceinline__ unsigned int elu2_pk(float t0, float t1) {
    f16x2 h = __builtin_bit_cast(f16x2, __builtin_amdgcn_cvt_pkrtz(t0, t1));
    const f16x2 z = {(_Float16)0.f, (_Float16)0.f};
    f16x2 m = __builtin_elementwise_min(h, z);
    f16x2 e;
    e[0] = __ocml_exp2_f16(m[0]);
    e[1] = __ocml_exp2_f16(m[1]);
    const f16x2 l2e2  = {(_Float16)L2E, (_Float16)L2E};
    const f16x2 nl2e2 = {(_Float16)(-L2E), (_Float16)(-L2E)};
    f16x2 el = __builtin_elementwise_fma(e, l2e2, nl2e2);
    f16x2 r = __builtin_elementwise_max(h, el);
    return __builtin_bit_cast(unsigned int, r);
}

// f32 pair -> packed f16 (RTZ), for the L1 im2col B build
__device__ __forceinline__ unsigned int cvt_pkrtz_u(float lo, float hi) {
    return __builtin_bit_cast(unsigned int, __builtin_amdgcn_cvt_pkrtz(lo, hi));
}

// ---------------------------------------------------------------------------
// Prep: one fragment per block. RTNE, zero-padded m/k.
// biasTap >= 0: bias folded at k == CI on that tap (x L2E), bias col holds 1.0.
// biasTap <  0: no in-matrix bias (bias via C-operand from the LDS table).
// Block 0 also writes the L2E-scaled f32 bias table (b3|b5) and re-arms bmE.
// ---------------------------------------------------------------------------
template<int M, int MT, int CI, int KS, int KT>
__device__ __forceinline__ void pack_one(const float* __restrict__ W,
                                         const float* __restrict__ Bias, int biasTap,
                                         unsigned short* __restrict__ dst,
                                         int f, int lane)
{
    const int ks = f % KS;
    const int fi = f / KS;
    const int mt = fi % MT;
    const int t  = fi / MT;
    const int m  = mt * 16 + (lane & 15);
    const int kb = ks * 32 + (lane >> 4) * 8;
    u16x8 v;
    #pragma unroll
    for (int j = 0; j < 8; ++j) {
        const int k = kb + j;
        float val = 0.f;
        if (m < M) {
            if (k < CI)                          val = W[(m * CI + k) * KT + t];
            else if (k == CI && t == biasTap)    val = Bias[m] * L2E;
        }
        v[j] = f2h_rtne(val);
    }
    *(u16x8*)(dst + (f * 64 + lane) * 8) = v;
}

__global__ __launch_bounds__(64) void prep_kernel(
    const float* __restrict__ w1, const float* __restrict__ b1,
    const float* __restrict__ w2, const float* __restrict__ b2,
    const float* __restrict__ w3, const float* __restrict__ b3,
    const float* __restrict__ w4, const float* __restrict__ b4,
    const float* __restrict__ w5, const float* __restrict__ b5,
    unsigned short* __restrict__ frags,
    float* __restrict__ biasT,
    float* __restrict__ bmE)
{
    const int lane = threadIdx.x;
    const int b = blockIdx.x;
    if (b == 0) {
        if (lane < 4) bmE[lane] = 0.f;   // "not ready" sentinel
        for (int i = lane; i < 100; i += 64) {
            const float v = (i < 80) ? b3[i] : b5[i - 80];
            biasT[i] = v * L2E;
        }
    }
    if (b < NFRAG2)
        pack_one<40, 3, 20, 1, 5>(w2, b2, 2, frags + F2, b, lane);
    else if (b < NFRAG2 + NFRAG3)
        pack_one<80, 5, 40, 2, 1>(w3, b3, -1, frags + F3, b - NFRAG2, lane);
    else if (b < NFRAG2 + NFRAG3 + NFRAG4) {
        // F4: k-PERMUTED so L3's D-layout feeds directly as B.
        // k' = ks*32 + q*8 + j  maps to logical channel:
        //   ks<2        : ch = ks*32 + (j>>2)*16 + q*4 + (j&3)
        //   ks==2, j<4  : ch = 64 + q*4 + j
        //   ks==2, j==4, q==0 : bias slot (B side provides 1.0)
        //   else        : zero
        const int f  = b - NFRAG2 - NFRAG3;   // f = mt*3 + ks
        const int ks = f % 3;
        const int mt = f / 3;
        const int m  = mt * 16 + (lane & 15);
        const int q  = lane >> 4;
        u16x8 v;
        #pragma unroll
        for (int j = 0; j < 8; ++j) {
            float val = 0.f;
            if (m < 40) {
                if (ks < 2) {
                    const int ch = ks * 32 + ((j >> 2) << 4) + q * 4 + (j & 3);
                    val = w4[m * 80 + ch];
                } else if (j < 4) {
                    const int ch = 64 + q * 4 + j;
                    val = w4[m * 80 + ch];
                } else if (j == 4 && q == 0) {
                    val = b4[m] * L2E;
                }
            }
            v[j] = f2h_rtne(val);
        }
        *(u16x8*)(frags + F4 + (f * 64 + lane) * 8) = v;
    }
    else if (b < NFRAG2 + NFRAG3 + NFRAG4 + NFRAG5)
        pack_one<20, 2, 40, 2, 3>(w5, b5, -1, frags + F5, b - NFRAG2 - NFRAG3 - NFRAG4, lane);
    else {
        // L1 fragments: A[m][k], k=0..4 -> w1 taps * L2E, k=5 -> bias * L2E.
        const int mt = b - (NPREP - 2);
        const int m  = mt * 16 + (lane & 15);
        const int kb = (lane >> 4) * 8;
        u16x8 v;
        #pragma unroll
        for (int j = 0; j < 8; ++j) {
            const int k = kb + j;
            float val = 0.f;
            if (m < 20) {
                if (k < 5)      val = w1[m * 5 + k] * L2E;
                else if (k == 5) val = b1[m] * L2E;
            }
            v[j] = f2h_rtne(val);
        }
        *(u16x8*)(frags + F1 + (mt * 64 + lane) * 8) = v;
    }
}

template<int NF>
__device__ __forceinline__ void load_A(const unsigned short* __restrict__ Af,
                                       int lane, f16x8* A) {
    #pragma unroll
    for (int f = 0; f < NF; ++f)
        A[f] = __builtin_bit_cast(f16x8, *(const u16x8*)(Af + (f * 64 + lane) * 8));
}

// ---------------------------------------------------------------------------
// Tap-decomposed MFMA layer; wave wv owns n-tiles 2wv, 2wv+1.
// ALL B-loads (both n-tiles) are hoisted above the MFMA+epilogue work so the
// epilogue LDS stores of tile 0 cannot block tile 1's loads.
// ---------------------------------------------------------------------------
template<int TAPS, int MT, int KS, typename Epi>
__device__ __forceinline__ void gemm_tap(const unsigned short* __restrict__ Af,
                                         const unsigned short* __restrict__ Bbuf,
                                         int SB, f32x4 Z4, Epi epi)
{
    const int lane = threadIdx.x & 63;
    const int wv   = threadIdx.x >> 6;
    const int n15  = lane & 15;
    const int quad = lane >> 4;

    f16x8 A[TAPS * MT * KS];
    load_A<TAPS * MT * KS>(Af, lane, A);

    f16x8 B[2][TAPS][KS];
    #pragma unroll
    for (int nt = 0; nt < 2; ++nt) {
        const int pos = (wv * 2 + nt) * 16 + n15;
        #pragma unroll
        for (int t = 0; t < TAPS; ++t)
            #pragma unroll
            for (int ks = 0; ks < KS; ++ks)
                B[nt][t][ks] = __builtin_bit_cast(f16x8,
                    *(const u16x8*)(Bbuf + (pos + t) * SB + ks * 32 + quad * 8));
    }

    #pragma unroll
    for (int nt = 0; nt < 2; ++nt) {
        const int pos = (wv * 2 + nt) * 16 + n15;
        #pragma unroll
        for (int mt = 0; mt < MT; ++mt) {
            f32x4 acc = __builtin_amdgcn_mfma_f32_16x16x32_f16(
                A[mt * KS], B[nt][0][0], Z4, 0, 0, 0);
            #pragma unroll
            for (int i = 1; i < TAPS * KS; ++i) {
                const int t = i / KS, ks = i - t * KS;
                acc = __builtin_amdgcn_mfma_f32_16x16x32_f16(
                    A[(t * MT + mt) * KS + ks], B[nt][t][ks], acc, 0, 0, 0);
            }
            epi(mt, pos, acc);
        }
    }
}

// ---------------------------------------------------------------------------
// WENO5 math given the 6-point u stencil and 3 bm values (rcp-based)
// ---------------------------------------------------------------------------
__device__ __forceinline__ float weno_math(float um2, float um1, float u0,
                                           float up1, float up2, float up3,
                                           float bmm, float bm0, float bmp)
{
    const float c1312 = 13.f / 12.f;
    const float s6 = 1.f / 6.f;

    const float f0p = (11.f * up1 - 7.f * up2 + 2.f * up3) * s6;
    const float f1p = (2.f * u0 + 5.f * up1 - up2) * s6;
    const float f2p = (-um1 + 5.f * u0 + 2.f * up1) * s6;
    const float f0n = (11.f * u0 - 7.f * up1 + 2.f * up2) * s6;
    const float f1n = (2.f * um1 + 5.f * u0 - up1) * s6;
    const float f2n = (-um2 + 5.f * um1 + 2.f * u0) * s6;

    float t0, t1;
    t0 = up1 - 2.f * up2 + up3;  t1 = 3.f * up1 - 4.f * up2 + up3;
    float bp0 = c1312 * t0 * t0 + 0.25f * t1 * t1;
    t0 = u0 - 2.f * up1 + up2;   t1 = u0 - up2;
    float bp1 = c1312 * t0 * t0 + 0.25f * t1 * t1;
    t0 = um1 - 2.f * u0 + up1;   t1 = um1 - 4.f * u0 + 3.f * up1;
    float bp2 = c1312 * t0 * t0 + 0.25f * t1 * t1;
    t0 = u0 - 2.f * up1 + up2;   t1 = 3.f * u0 - 4.f * up1 + up2;
    float bn0 = c1312 * t0 * t0 + 0.25f * t1 * t1;
    t0 = um1 - 2.f * u0 + up1;   t1 = um1 - up1;
    float bn1 = c1312 * t0 * t0 + 0.25f * t1 * t1;
    t0 = um2 - 2.f * um1 + u0;   t1 = um2 - 4.f * um1 + 3.f * u0;
    float bn2 = c1312 * t0 * t0 + 0.25f * t1 * t1;

    bp0 *= bmp; bp1 *= bm0; bp2 *= bmm;
    bn0 *= bmp; bn1 *= bm0; bn2 *= bmm;

    const float E = 1e-13f;
    float brs, e, r0, r1, r2, o0, o1, o2;

    brs = bp2 - bp0; brs *= brs;
    e = E + bp0; e *= e; r0 = fastrcp(e);
    e = E + bp1; e *= e; r1 = fastrcp(e);
    e = E + bp2; e *= e; r2 = fastrcp(e);
    o0 = 0.1f * fmaf(brs, r0, 1.f);
    o1 = 0.6f * fmaf(brs, r1, 1.f);
    o2 = 0.3f * fmaf(brs, r2, 1.f);
    const float fluxp = (o0 * f0p + o1 * f1p + o2 * f2p) * fastrcp(o0 + o1 + o2);

    brs = bn2 - bn0; brs *= brs;
    e = E + bn0; e *= e; r0 = fastrcp(e);
    e = E + bn1; e *= e; r1 = fastrcp(e);
    e = E + bn2; e *= e; r2 = fastrcp(e);
    o0 = 0.1f * fmaf(brs, r0, 1.f);
    o1 = 0.6f * fmaf(brs, r1, 1.f);
    o2 = 0.3f * fmaf(brs, r2, 1.f);
    const float fluxn = (o0 * f0n + o1 * f1n + o2 * f2n) * fastrcp(o0 + o1 + o2);

    return fluxp - fluxn;
}

// ---------------------------------------------------------------------------
// Fused CNN + WENO (256 threads = 4 waves; two n-tiles per wave).
// ---------------------------------------------------------------------------
__global__ __launch_bounds__(BLK, 5) void cnn_weno_kernel(
    const float* __restrict__ u,
    const float* __restrict__ w6, const float* __restrict__ b6,
    const unsigned short* __restrict__ frags,
    const float* __restrict__ biasTg,
    float* __restrict__ bmE,
    float* __restrict__ out)
{
    // ---- tail block: spin on the 4 ready-slots, then patch wrap points ----
    if (blockIdx.x == NBLK) {
        if (threadIdx.x == 0) {
            float b0, b1, b2, b3;
            for (;;) {
                b0 = __hip_atomic_load(&bmE[0], __ATOMIC_ACQUIRE, __HIP_MEMORY_SCOPE_AGENT);
                b1 = __hip_atomic_load(&bmE[1], __ATOMIC_ACQUIRE, __HIP_MEMORY_SCOPE_AGENT);
                b2 = __hip_atomic_load(&bmE[2], __ATOMIC_ACQUIRE, __HIP_MEMORY_SCOPE_AGENT);
                b3 = __hip_atomic_load(&bmE[3], __ATOMIC_ACQUIRE, __HIP_MEMORY_SCOPE_AGENT);
                if (b0 != 0.f && b1 != 0.f && b2 != 0.f && b3 != 0.f) break;
                __builtin_amdgcn_s_sleep(2);
            }
            out[0] = weno_math(u[N_PTS - 2], u[N_PTS - 1], u[0],
                               u[1], u[2], u[3], b3, b0, b1);
            out[N_PTS - 1] = weno_math(u[N_PTS - 3], u[N_PTS - 2], u[N_PTS - 1],
                                       u[0], u[1], u[2], b2, b3, b0);
        }
        return;
    }

    extern __shared__ char smem[];
    unsigned short* act1 = (unsigned short*)(smem + SLOTA_OFF);  // [132][40], dead after P3
    unsigned short* act4 = (unsigned short*)(smem + SLOTA_OFF);  // [<=131][40], written P4
    unsigned short* act2 = (unsigned short*)(smem + SLOTB_OFF);  // [129][40]
    float* sbias = (float*)(smem + SBIAS_OFF); // 100: b3[80] | b5[20]  (x L2E)
    float* sdif = (float*)(smem + TAIL_OFF);   // 132
    float* sw6  = sdif + 132;                  // 20
    float* sb6  = sw6 + 20;                    // 1
    float* sbm  = sb6 + 1;                     // 118  (sbm[j] = bm at q = j + 5)
    float* su   = sbm + 118;                   // 121  (su[j] = u[(i0-2+j) & MASK])

    const int tid  = threadIdx.x;
    const int lane = tid & 63;
    const int wv   = tid >> 6;
    const int n15  = lane & 15;
    const int quad = lane >> 4;
    const int i0   = blockIdx.x * POUT;
    const bool edge = (blockIdx.x == 0) || (blockIdx.x >= NBLK - 1);

    const f32x4 Z4 = {0.f, 0.f, 0.f, 0.f};     // hoisted zero C-operand

    // ---- phase 1: stale-read guards + bias table + staging ----
    {
        const u16x8 z8 = {0, 0, 0, 0, 0, 0, 0, 0};
        // act1 rows 128..131 (cols 0..39): L2 tap reads + doubles as act4
        // rows 128..131 guard (alias). act2 r128 c0..23: L3 ks-spill from r127.
        // act4 r0 c0..39: finite-only (L5 pos<5 outputs are discarded); P2
        // overwrites c0..31 with act1 data, c32..39 keep the zero.
        if (tid < 20)       *(u16x8*)(act1 + 128 * ST1 + tid * 8) = z8;
        else if (tid < 23)  *(u16x8*)(act2 + 128 * ST2 + (tid - 20) * 8) = z8;
        else if (tid < 28)  *(u16x8*)(act4 + (tid - 23) * 8) = z8;
        if (tid < 100) sbias[tid] = biasTg[tid];
    }
    if (!edge) {   // fast path: no boundary handling needed (uniform branch)
        for (int d = tid; d < 132; d += BLK) {
            const int g = i0 - 10 + d;
            sdif[d] = 0.5f * (u[g + 1] - u[g - 1]);
        }
        for (int j = tid; j < 121; j += BLK)
            su[j] = u[i0 - 2 + j];
    } else {
        for (int d = tid; d < 132; d += BLK) {
            const int g = i0 - 10 + d;
            float v = 0.f;
            if (g >= 0 && g < N_PTS) {
                if (g == 0)              v = u[1] - u[0];
                else if (g == N_PTS - 1) v = u[N_PTS - 1] - u[N_PTS - 2];
                else                     v = 0.5f * (u[g + 1] - u[g - 1]);
            }
            sdif[d] = v;
        }
        for (int j = tid; j < 121; j += BLK)
            su[j] = u[(i0 - 2 + j) & MASK];
    }
    if (tid < 20)       sw6[tid] = w6[tid] * LN2;   // log2e-folding: w6*ln2
    else if (tid == 20) sb6[0] = b6[0];
    __syncthreads();

    // ---- phase 2: L1 via MFMA (im2col B from sdif; taps+bias in k) ----
    {
        f16x8 A1[2];
        load_A<2>(frags + F1, lane, A1);
        float s[2][5];
        #pragma unroll
        for (int nt = 0; nt < 2; ++nt) {
            const int pos = (wv * 2 + nt) * 16 + n15;
            #pragma unroll
            for (int j = 0; j < 5; ++j)
                s[nt][j] = sdif[pos + j];
        }
        #pragma unroll
        for (int nt = 0; nt < 2; ++nt) {
            const int pos = (wv * 2 + nt) * 16 + n15;
            uint4 bd;
            bd.x = cvt_pkrtz_u(s[nt][0], s[nt][1]);
            bd.y = cvt_pkrtz_u(s[nt][2], s[nt][3]);
            bd.z = cvt_pkrtz_u(s[nt][4], 1.0f);    // k=5 bias slot
            bd.w = 0u;
            const f16x8 B = __builtin_bit_cast(f16x8, bd);
            const f32x4 a0 = __builtin_amdgcn_mfma_f32_16x16x32_f16(A1[0], B, Z4, 0, 0, 0);
            const f32x4 a1 = __builtin_amdgcn_mfma_f32_16x16x32_f16(A1[1], B, Z4, 0, 0, 0);
            bool oor = false;
            if (edge) {
                const int g = i0 + pos - 8;   // act1 row pos <-> g
                oor = ((unsigned)g >= (unsigned)N_PTS);
            }
            {   // ch 0..15
                uint2 w;
                w.x = elu2_pk(a0[0], a0[1]); w.y = elu2_pk(a0[2], a0[3]);
                if (oor) { w.x = 0u; w.y = 0u; }
                *(uint2*)(act1 + pos * ST1 + quad * 4) = w;
            }
            {   // ch 16..19 + bias col 20 (L2 bias in-B) + zero pad 24..31
                uint2 w;
                if (quad == 0) {
                    w.x = elu2_pk(a1[0], a1[1]); w.y = elu2_pk(a1[2], a1[3]);
                    if (oor) { w.x = 0u; w.y = 0u; }
                } else if (quad == 1) {
                    w.x = (unsigned)F16_ONE; w.y = 0u;
                } else {
                    w.x = 0u; w.y = 0u;
                }
                *(uint2*)(act1 + pos * ST1 + 16 + quad * 4) = w;
            }
        }
    }
    __syncthreads();

    // ---- phase 3: L2 (40ch, 5 taps, bias folded in-B) act1 -> act2 ----
    gemm_tap<5, 3, 1>(frags + F2, act1, ST1, Z4,
        [&](int mt, int pos, f32x4 acc) {
            if (mt < 2 || quad < 2) {        // ch0 < 40
                uint2 w;
                w.x = elu2_pk(acc[0], acc[1]); w.y = elu2_pk(acc[2], acc[3]);
                if (edge) {
                    const int g = i0 - GOFF + pos;
                    if ((unsigned)g >= (unsigned)N_PTS) { w.x = 0u; w.y = 0u; }
                }
                *(uint2*)(act2 + pos * ST2 + mt * 16 + quad * 4) = w;
            }
        });
    __syncthreads();

    // ---- phase 4: L3+L4 FUSED in registers (both k=1) act2 -> act4.
    //      L3 bias via C-operand (LDS sbias); L3's D-layout feeds L4's B
    //      directly via the k-permuted F4 frags (L4 bias in-B).
    {
        unsigned int p[2][5][2];   // packed elu'(L3) f16 pairs (static-indexed)
        {
            f16x8 A3[10];
            load_A<10>(frags + F3, lane, A3);
            f16x8 B3[2][2];
            #pragma unroll
            for (int nt = 0; nt < 2; ++nt) {
                const int pos = (wv * 2 + nt) * 16 + n15;
                #pragma unroll
                for (int ks = 0; ks < 2; ++ks)
                    B3[nt][ks] = __builtin_bit_cast(f16x8,
                        *(const u16x8*)(act2 + pos * ST2 + ks * 32 + quad * 8));
            }
            #pragma unroll
            for (int mt = 0; mt < 5; ++mt) {
                const f32x4 c3 = *(const f32x4*)(sbias + mt * 16 + quad * 4);
                #pragma unroll
                for (int nt = 0; nt < 2; ++nt) {
                    f32x4 acc = __builtin_amdgcn_mfma_f32_16x16x32_f16(
                        A3[mt * 2 + 0], B3[nt][0], c3, 0, 0, 0);
                    acc = __builtin_amdgcn_mfma_f32_16x16x32_f16(
                        A3[mt * 2 + 1], B3[nt][1], acc, 0, 0, 0);
                    p[nt][mt][0] = elu2_pk(acc[0], acc[1]);
                    p[nt][mt][1] = elu2_pk(acc[2], acc[3]);
                }
            }
        }
        {
            f16x8 A4[9];
            load_A<9>(frags + F4, lane, A4);
            const unsigned int biasw = (quad == 0) ? (unsigned)F16_ONE : 0u;
            #pragma unroll
            for (int nt = 0; nt < 2; ++nt) {
                const int pos = (wv * 2 + nt) * 16 + n15;
                uint4 w0, w1, w2;
                w0.x = p[nt][0][0]; w0.y = p[nt][0][1]; w0.z = p[nt][1][0]; w0.w = p[nt][1][1];
                w1.x = p[nt][2][0]; w1.y = p[nt][2][1]; w1.z = p[nt][3][0]; w1.w = p[nt][3][1];
                w2.x = p[nt][4][0]; w2.y = p[nt][4][1]; w2.z = biasw;       w2.w = 0u;
                f16x8 B4[3];
                B4[0] = __builtin_bit_cast(f16x8, w0);
                B4[1] = __builtin_bit_cast(f16x8, w1);
                B4[2] = __builtin_bit_cast(f16x8, w2);
                #pragma unroll
                for (int mt = 0; mt < 3; ++mt) {
                    f32x4 acc = __builtin_amdgcn_mfma_f32_16x16x32_f16(
                        A4[mt * 3 + 0], B4[0], Z4, 0, 0, 0);
                    acc = __builtin_amdgcn_mfma_f32_16x16x32_f16(
                        A4[mt * 3 + 1], B4[1], acc, 0, 0, 0);
                    acc = __builtin_amdgcn_mfma_f32_16x16x32_f16(
                        A4[mt * 3 + 2], B4[2], acc, 0, 0, 0);
                    if (mt < 2 || quad < 2) {    // ch0 < 40
                        uint2 w;
                        w.x = elu2_pk(acc[0], acc[1]); w.y = elu2_pk(acc[2], acc[3]);
                        if (edge) {
                            const int g = i0 - GOFF + pos;
                            if ((unsigned)g >= (unsigned)N_PTS) { w.x = 0u; w.y = 0u; }
                        }
                        *(uint2*)(act4 + (pos + 1) * ST4 + mt * 16 + quad * 4) = w;
                    }
                }
            }
        }
    }
    __syncthreads();

    // ---- phase 6: L5 (20ch, 3 taps, bias via C) + L6 + sigmoid -> sbm ----
    {
        f16x8 A5[12];
        load_A<12>(frags + F5, lane, A5);
        const f32x4 c0 = *(const f32x4*)(sbias + 80 + quad * 4);
        const f32x4 c1 = *(const f32x4*)(sbias + 80 + 16);
        #pragma unroll
        for (int nt = 0; nt < 2; ++nt) {
            const int pos = (wv * 2 + nt) * 16 + n15;
            f16x8 B[3][2];
            #pragma unroll
            for (int t = 0; t < 3; ++t)
                #pragma unroll
                for (int ks = 0; ks < 2; ++ks)
                    B[t][ks] = __builtin_bit_cast(f16x8,
                        *(const u16x8*)(act4 + (pos + t) * ST4 + ks * 32 + quad * 8));
            f32x4 a0 = __builtin_amdgcn_mfma_f32_16x16x32_f16(A5[0], B[0][0], c0, 0, 0, 0);
            f32x4 a1 = __builtin_amdgcn_mfma_f32_16x16x32_f16(A5[2], B[0][0], c1, 0, 0, 0);
            #pragma unroll
            for (int i = 1; i < 6; ++i) {
                const int t = i >> 1, ks = i & 1;
                a0 = __builtin_amdgcn_mfma_f32_16x16x32_f16(
                    A5[(t * 2 + 0) * 2 + ks], B[t][ks], a0, 0, 0, 0);
                a1 = __builtin_amdgcn_mfma_f32_16x16x32_f16(
                    A5[(t * 2 + 1) * 2 + ks], B[t][ks], a1, 0, 0, 0);
            }
            float partial = 0.f;
            const int c0i = quad * 4;
            #pragma unroll
            for (int r = 0; r < 4; ++r)
                partial += sw6[c0i + r] * elu_t(a0[r]);
            if (quad == 0) {
                #pragma unroll
                for (int r = 0; r < 4; ++r)
                    partial += sw6[16 + r] * elu_t(a1[r]);
            }
            partial += __shfl_xor(partial, 16, 64);
            partial += __shfl_xor(partial, 32, 64);
            if (quad == 0) {
                const float bmv = fastrcp(1.f + __expf(-(partial + sb6[0]))) + 0.1f;
                if (pos >= 5 && pos < 123) sbm[pos - 5] = bmv;
                if (edge) {
                    const int g = i0 - GOFF + pos;
                    if (blockIdx.x == 0) {
                        if (g == 0)
                            __hip_atomic_store(&bmE[0], bmv, __ATOMIC_RELEASE, __HIP_MEMORY_SCOPE_AGENT);
                        else if (g == 1)
                            __hip_atomic_store(&bmE[1], bmv, __ATOMIC_RELEASE, __HIP_MEMORY_SCOPE_AGENT);
                    }
                    if (blockIdx.x == NBLK - 1) {
                        if (g == N_PTS - 2)
                            __hip_atomic_store(&bmE[2], bmv, __ATOMIC_RELEASE, __HIP_MEMORY_SCOPE_AGENT);
                        else if (g == N_PTS - 1)
                            __hip_atomic_store(&bmE[3], bmv, __ATOMIC_RELEASE, __HIP_MEMORY_SCOPE_AGENT);
                    }
                }
            }
        }
    }
    __syncthreads();

    // ---- phase 7: WENO from the staged u tile (wrap handled at staging) ----
    if (tid < POUT) {
        const int g = i0 + tid;
        if (g < N_PTS && g != 0 && g != N_PTS - 1) {
            out[g] = weno_math(su[tid], su[tid + 1], su[tid + 2],
                               su[tid + 3], su[tid + 4], su[tid + 5],
                               sbm[tid], sbm[tid + 1], sbm[tid + 2]);
        }
    }
}

extern "C" void kernel_launch(void* const* d_in, const int* in_sizes, int n_in,
                              void* d_out, int out_size, void* d_ws, size_t ws_size,
                              hipStream_t stream) {
    const float* u  = (const float*)d_in[0];
    const float* w1 = (const float*)d_in[1];
    const float* b1 = (const float*)d_in[2];
    const float* w2 = (const float*)d_in[3];
    const float* b2 = (const float*)d_in[4];
    const float* w3 = (const float*)d_in[5];
    const float* b3 = (const float*)d_in[6];
    const float* w4 = (const float*)d_in[7];
    const float* b4 = (const float*)d_in[8];
    const float* w5 = (const float*)d_in[9];
    const float* b5 = (const float*)d_in[10];
    const float* w6 = (const float*)d_in[11];
    const float* b6 = (const float*)d_in[12];

    unsigned short* frags = (unsigned short*)d_ws;            // 49152 B
    float* biasT = (float*)((char*)d_ws + BIAS_OFF);          // 100 f32 (x L2E)
    float* bmE = (float*)((char*)d_ws + BME_OFF);             // 4 f32 ready-slots

    (void)hipFuncSetAttribute((const void*)cnn_weno_kernel,
                              hipFuncAttributeMaxDynamicSharedMemorySize,
                              SMEM_BYTES);

    prep_kernel<<<NPREP, 64, 0, stream>>>(w1, b1, w2, b2, w3, b3, w4, b4, w5, b5,
                                          frags, biasT, bmE);
    cnn_weno_kernel<<<NBLK + 1, BLK, SMEM_BYTES, stream>>>(u, w6, b6, frags, biasT,
                                                           bmE, (float*)d_out);
}